// Round 18
// baseline (229.457 us; speedup 1.0000x reference)
//
#include <hip/hip_runtime.h>
#include <hip/hip_bf16.h>

typedef __attribute__((ext_vector_type(4))) float f32x4;
typedef __attribute__((ext_vector_type(8))) short s16x8;
typedef __attribute__((ext_vector_type(4))) int i32x4;
typedef __attribute__((ext_vector_type(4))) unsigned short u16x4;

#define NEG_INF_F (-9.0e15f)
#define LOG2E_F 1.44269504088896340736f
#define N_ROWS 8192
#define F_DIM 256

__device__ __forceinline__ unsigned short f2bf(float f) {
    unsigned int u = __builtin_bit_cast(unsigned int, f);
    u += 0x7fffu + ((u >> 16) & 1u);   // round-to-nearest-even
    return (unsigned short)(u >> 16);
}

__device__ __forceinline__ float fast_exp2(float x) {
#if __has_builtin(__builtin_amdgcn_exp2f)
    return __builtin_amdgcn_exp2f(x);   // raw v_exp_f32; big-neg -> exactly 0.0
#else
    return exp2f(x);
#endif
}

__device__ __forceinline__ short f2bf_fast(float f) {
    __hip_bfloat16 b = __float2bfloat16(f);   // native cast -> v_cvt_pk_bf16_f32 pairs
    return __builtin_bit_cast(short, b);
}

// ------------- Kernel 01: fused k1 (GEMM) + kva/k1b (scores) + k0 (pack) -
// blocks [0,512): hTp = bf16(x@W^T) packed [k/8][feat][k%8]
// blocks [512,768): va = W^T a (in LDS, redundant per block); s1,s2 = x@va
// blocks [768,4608): adj -> bitmask via ballot (grid-stride)
// HBM-bound pack overlaps compute-bound GEMM across CUs in one launch.
__global__ __launch_bounds__(256) void k01(const float* __restrict__ x,
                                           const float* __restrict__ W,
                                           unsigned short* __restrict__ hTp,
                                           const float* __restrict__ a,
                                           const int* __restrict__ adj,
                                           unsigned long long* __restrict__ mask,
                                           float* __restrict__ s1,
                                           float* __restrict__ s2) {
    __shared__ float xT[128][64];
    __shared__ float wT[128][64];
    const int bb = (int)blockIdx.x;
    const int tid = threadIdx.x;

    if (bb < 512) {
        // ---- k1 body (r9-proven) ----
        const int rb = bb >> 2, fbk = bb & 3;
        const int row0 = rb * 64, f0 = fbk * 64;
        const int rs = tid >> 2, cs = tid & 3;
        const int r0 = (tid & 15) * 4, fc = (tid >> 4) * 4;
        float acc[4][4];
#pragma unroll
        for (int i = 0; i < 4; ++i)
#pragma unroll
            for (int j = 0; j < 4; ++j) acc[i][j] = 0.0f;

#pragma unroll 1
        for (int p = 0; p < 2; ++p) {
            const int kb = p * 128;
            if (p) __syncthreads();
            const float* xrow = x + (size_t)(row0 + rs) * F_DIM + kb + cs * 32;
            const float* wrow = W + (size_t)(f0 + rs) * F_DIM + kb + cs * 32;
#pragma unroll
            for (int i = 0; i < 8; ++i) {
                f32x4 xv = *(const f32x4*)(xrow + i * 4);
                f32x4 wv = *(const f32x4*)(wrow + i * 4);
#pragma unroll
                for (int jj = 0; jj < 4; ++jj) {
                    xT[cs * 32 + i * 4 + jj][rs] = xv[jj];
                    wT[cs * 32 + i * 4 + jj][rs] = wv[jj];
                }
            }
            __syncthreads();
#pragma unroll 4
            for (int kk = 0; kk < 128; ++kk) {
                f32x4 xv = *(const f32x4*)&xT[kk][r0];
                f32x4 wv = *(const f32x4*)&wT[kk][fc];
#pragma unroll
                for (int i = 0; i < 4; ++i)
#pragma unroll
                    for (int j = 0; j < 4; ++j)
                        acc[i][j] = fmaf(xv[i], wv[j], acc[i][j]);
            }
        }
        const int kblk = (row0 + r0) >> 3, kslot = (row0 + r0) & 7;
#pragma unroll
        for (int j = 0; j < 4; ++j) {
            u16x4 t;
            t[0] = f2bf(acc[0][j]); t[1] = f2bf(acc[1][j]);
            t[2] = f2bf(acc[2][j]); t[3] = f2bf(acc[3][j]);
            *(u16x4*)(hTp + (size_t)kblk * 2048 + (f0 + fc + j) * 8 + kslot) = t;
        }
    } else if (bb < 768) {
        // ---- kva (redundant per block, into LDS) + k1b body ----
        float* va = &xT[0][0];                  // 512 floats of LDS
        {
            const int k = tid;
            const float* a1p = a;
            const float* a2p = a + 256;
            float u0 = 0.f, u1 = 0.f, v0 = 0.f, v1 = 0.f;
#pragma unroll 8
            for (int f = 0; f < 256; f += 2) {
                const float w0 = W[(size_t)f * 256 + k];
                const float w1 = W[(size_t)(f + 1) * 256 + k];
                u0 = fmaf(a1p[f], w0, u0);  u1 = fmaf(a1p[f + 1], w1, u1);
                v0 = fmaf(a2p[f], w0, v0);  v1 = fmaf(a2p[f + 1], w1, v1);
            }
            va[k] = u0 + u1;
            va[256 + k] = v0 + v1;
        }
        __syncthreads();
        const int lane = tid & 63, w = tid >> 6;
        f32x4 a1 = *(const f32x4*)(va + lane * 4);
        f32x4 a2 = *(const f32x4*)(va + 256 + lane * 4);
        const int row0 = (bb - 512) * 32 + w * 8;
#pragma unroll 1
        for (int rr = 0; rr < 8; ++rr) {
            const int row = row0 + rr;
            f32x4 hv = *(const f32x4*)(x + (size_t)row * F_DIM + lane * 4);
            float p1 = hv[0] * a1[0] + hv[1] * a1[1] + hv[2] * a1[2] + hv[3] * a1[3];
            float p2 = hv[0] * a2[0] + hv[1] * a2[1] + hv[2] * a2[2] + hv[3] * a2[3];
#pragma unroll
            for (int o = 32; o; o >>= 1) { p1 += __shfl_xor(p1, o); p2 += __shfl_xor(p2, o); }
            if (lane == 0) { s1[row] = p1; s2[row] = p2; }
        }
    } else {
        // ---- k0 ballot pack body (r6-proven; bit order == per-thread r7) ----
        const int lane = tid & 63;
        const int gw = ((bb - 768) * 256 + tid) >> 6;
        const int nw = (3840 * 256) >> 6;
#pragma unroll 1
        for (int w4 = gw * 4; w4 < (N_ROWS * N_ROWS / 64); w4 += nw * 4) {
            const size_t base = (size_t)w4 * 64 + lane;
            const int v0 = adj[base];
            const int v1 = adj[base + 64];
            const int v2 = adj[base + 128];
            const int v3 = adj[base + 192];
            const unsigned long long b0 = __ballot(v0 > 0);
            const unsigned long long b1 = __ballot(v1 > 0);
            const unsigned long long b2 = __ballot(v2 > 0);
            const unsigned long long b3 = __ballot(v3 > 0);
            if (lane == 0) {
                mask[w4] = b0; mask[w4 + 1] = b1; mask[w4 + 2] = b2; mask[w4 + 3] = b3;
            }
        }
    }
}

// ------------- Kernel 1c: M[i] = max over unmasked j of s2[j] ------------
__global__ __launch_bounds__(256) void kmax(const unsigned* __restrict__ mask32,
                                            const float* __restrict__ s2,
                                            float* __restrict__ Mrow) {
    __shared__ float s2l[8192];
    const int tid = threadIdx.x, lane = tid & 63, wv = tid >> 6;
#pragma unroll
    for (int i = 0; i < 8; ++i) {
        const int idx = (i * 256 + tid) * 4;
        *(f32x4*)&s2l[idx] = *(const f32x4*)(s2 + idx);
    }
    __syncthreads();
    const int row = (int)blockIdx.x * 4 + wv;
    const unsigned* __restrict__ mr = mask32 + (size_t)row * 256;
    float vmax = NEG_INF_F;
#pragma unroll 1
    for (int wi = 0; wi < 4; ++wi) {
        const unsigned m = mr[lane * 4 + wi];
        const int kb = (lane * 4 + wi) * 32;
#pragma unroll
        for (int cc = 0; cc < 8; ++cc) {
            const int c = (cc + lane) & 7;
            f32x4 v = *(const f32x4*)&s2l[kb + c * 4];
            const unsigned sh = (unsigned)(c * 4);
            vmax = fmaxf(vmax, ((m >> (sh + 0)) & 1u) ? v[0] : NEG_INF_F);
            vmax = fmaxf(vmax, ((m >> (sh + 1)) & 1u) ? v[1] : NEG_INF_F);
            vmax = fmaxf(vmax, ((m >> (sh + 2)) & 1u) ? v[2] : NEG_INF_F);
            vmax = fmaxf(vmax, ((m >> (sh + 3)) & 1u) ? v[3] : NEG_INF_F);
        }
    }
#pragma unroll
    for (int o = 32; o; o >>= 1) vmax = fmaxf(vmax, __shfl_xor(vmax, o));
    if (lane == 0) Mrow[row] = vmax;
}

// ------------- Kernel 2: fused masked softmax + PV -----------------------
// r11 structure with: (a) fh-per-XCD affinity (XCDs 0-3 -> feat-half 0,
// 4-7 -> half 1: each XCD L2 holds only its 2MB hTp slice); (b) depth-3
// prefetch via 4 named buffers (VGPR ~230 stays in the 129-256 occupancy bin).

#define P_ONE(D, SV, BIT, SI, MC)                                             \
    { float t_ = (SI) + (SV); t_ = fmaxf(t_, 0.2f * t_);                      \
      D = fast_exp2(fmaf(((bb_ & (BIT)) ? t_ : NEG_INF_F), LOG2E_F, -(MC))); }

#define RG_STEP(ACC, ACCL, BFR, MW, SI, MC)                                   \
    {                                                                         \
        const unsigned bb_ = ((MW) >> koff) & 0xffu;                          \
        float p0_, p1_, p2_, p3_, p4_, p5_, p6_, p7_;                         \
        P_ONE(p0_, svA_[0], 1u, SI, MC)   P_ONE(p1_, svA_[1], 2u, SI, MC)     \
        P_ONE(p2_, svA_[2], 4u, SI, MC)   P_ONE(p3_, svA_[3], 8u, SI, MC)     \
        P_ONE(p4_, svB_[0], 16u, SI, MC)  P_ONE(p5_, svB_[1], 32u, SI, MC)    \
        P_ONE(p6_, svB_[2], 64u, SI, MC)  P_ONE(p7_, svB_[3], 128u, SI, MC)   \
        s16x8 af_;                                                            \
        af_[0] = f2bf_fast(p0_); af_[1] = f2bf_fast(p1_);                     \
        af_[2] = f2bf_fast(p2_); af_[3] = f2bf_fast(p3_);                     \
        af_[4] = f2bf_fast(p4_); af_[5] = f2bf_fast(p5_);                     \
        af_[6] = f2bf_fast(p6_); af_[7] = f2bf_fast(p7_);                     \
        _Pragma("unroll")                                                     \
        for (int nt_ = 0; nt_ < 8; ++nt_)                                     \
            ACC[nt_] = __builtin_amdgcn_mfma_f32_16x16x32_bf16(af_, BFR[nt_], ACC[nt_], 0, 0, 0); \
        ACCL = __builtin_amdgcn_mfma_f32_16x16x32_bf16(af_, bones, ACCL, 0, 0, 0); \
    }

#define STEP4(BFR, T)                                                         \
    {                                                                         \
        const int k0_ = kbase + (T) * 32;                                     \
        const unsigned mwA_ = mA32[k0_ >> 5];                                 \
        const unsigned mwB_ = mB32[k0_ >> 5];                                 \
        const f32x4 svA_ = *(const f32x4*)(s2 + k0_ + koff);                  \
        const f32x4 svB_ = *(const f32x4*)(s2 + k0_ + koff + 4);              \
        RG_STEP(accA, accLA, BFR, mwA_, siA, mCA)                             \
        RG_STEP(accB, accLB, BFR, mwB_, siB, mCB)                             \
    }

#define LOAD_B(DST, T)                                                        \
    {                                                                         \
        const int kt_ = kbase + (T) * 32;                                     \
        _Pragma("unroll")                                                     \
        for (int nt_ = 0; nt_ < 8; ++nt_)                                     \
            DST[nt_] = *(const s16x8*)(hTp + (unsigned)((kt_ >> 3) + kg) * 2048u + vb + (unsigned)(nt_ * 128)); \
    }

__global__ __launch_bounds__(256) void k2_attn(const unsigned* __restrict__ mask32,
                                               const unsigned short* __restrict__ hTp,
                                               const float* __restrict__ s1,
                                               const float* __restrict__ s2,
                                               const float* __restrict__ Mrow,
                                               float* __restrict__ out) {
    __shared__ float lbuf[4][2][16];            // [wc][rg][row]
    __shared__ float accbuf[3][16][132];        // [wc-1][row][feat] (+4 pad)

    const int tid = threadIdx.x;
    const int lane = tid & 63;
    const int wc = tid >> 6;                    // 0..3 key-chunk
    const int lane15 = lane & 15, kg = lane >> 4, koff = kg * 8;
    // fh-per-XCD mapping (bijective): xcd = b&7; fh = xcd>>2; rb = (b>>3)*4 + (xcd&3)
    const int b = (int)blockIdx.x;
    const int xcd = b & 7;
    const int fh = xcd >> 2;
    const int rowblk = (b >> 3) * 4 + (xcd & 3);
    const int row0 = rowblk * 32;
    const int mrowA = row0 + lane15, mrowB = row0 + 16 + lane15;
    const int fb = fh * 128;
    const int kbase = wc * 2048;
    const float siA = s1[mrowA], siB = s1[mrowB];
    const float tmxA = siA + Mrow[mrowA], tmxB = siB + Mrow[mrowB];
    const float mCA = fmaxf(tmxA, 0.2f * tmxA) * LOG2E_F;
    const float mCB = fmaxf(tmxB, 0.2f * tmxB) * LOG2E_F;
    const unsigned* __restrict__ mA32 = mask32 + (size_t)mrowA * 256;
    const unsigned* __restrict__ mB32 = mask32 + (size_t)mrowB * 256;

    f32x4 accA[8], accB[8], accLA, accLB;
#pragma unroll
    for (int nt = 0; nt < 8; ++nt) {
        f32x4 z = {0.f, 0.f, 0.f, 0.f};
        accA[nt] = z; accB[nt] = z;
    }
    { f32x4 z = {0.f, 0.f, 0.f, 0.f}; accLA = z; accLB = z; }

    s16x8 bones;
#pragma unroll
    for (int j = 0; j < 8; ++j) bones[j] = (short)0x3F80;   // bf16 1.0

    const unsigned vb = (unsigned)(fb + lane15) * 8u;

    s16x8 b0[8], b1[8], b2[8], b3[8];
    LOAD_B(b0, 0) LOAD_B(b1, 1) LOAD_B(b2, 2) LOAD_B(b3, 3)

#pragma unroll 1
    for (int it = 0; it < 64; it += 4) {
        STEP4(b0, it)     LOAD_B(b0, (it + 4) & 63)   // wrap: dummy, unused
        STEP4(b1, it + 1) LOAD_B(b1, (it + 5) & 63)
        STEP4(b2, it + 2) LOAD_B(b2, (it + 6) & 63)
        STEP4(b3, it + 3) LOAD_B(b3, (it + 7) & 63)
    }

    // l: ones-MFMA already reduced over keys; every D column holds the row sum.
    if (lane15 == 0) {
#pragma unroll
        for (int r = 0; r < 4; ++r) {
            lbuf[wc][0][kg * 4 + r] = accLA[r];
            lbuf[wc][1][kg * 4 + r] = accLB[r];
        }
    }

    // ---- phase A: merge + write row-group 0 ----
    if (wc > 0) {
#pragma unroll
        for (int r = 0; r < 4; ++r)
#pragma unroll
            for (int nt = 0; nt < 8; ++nt)
                accbuf[wc - 1][kg * 4 + r][nt * 16 + lane15] = accA[nt][r];
    }
    __syncthreads();
    if (wc == 0) {
#pragma unroll
        for (int r = 0; r < 4; ++r) {
            const int dr = kg * 4 + r;
            const float lt = (lbuf[0][0][dr] + lbuf[1][0][dr]) + (lbuf[2][0][dr] + lbuf[3][0][dr]);
            const float inv = 1.0f / lt;
            float* orow_p = out + (size_t)(row0 + dr) * F_DIM + fb + lane15;
#pragma unroll
            for (int nt = 0; nt < 8; ++nt) {
                const float v = accA[nt][r] + accbuf[0][dr][nt * 16 + lane15]
                              + accbuf[1][dr][nt * 16 + lane15]
                              + accbuf[2][dr][nt * 16 + lane15];
                orow_p[nt * 16] = v * inv;
            }
        }
    }
    __syncthreads();

    // ---- phase B: merge + write row-group 1 ----
    if (wc > 0) {
#pragma unroll
        for (int r = 0; r < 4; ++r)
#pragma unroll
            for (int nt = 0; nt < 8; ++nt)
                accbuf[wc - 1][kg * 4 + r][nt * 16 + lane15] = accB[nt][r];
    }
    __syncthreads();
    if (wc == 0) {
#pragma unroll
        for (int r = 0; r < 4; ++r) {
            const int dr = kg * 4 + r;
            const float lt = (lbuf[0][1][dr] + lbuf[1][1][dr]) + (lbuf[2][1][dr] + lbuf[3][1][dr]);
            const float inv = 1.0f / lt;
            float* orow_p = out + (size_t)(row0 + 16 + dr) * F_DIM + fb + lane15;
#pragma unroll
            for (int nt = 0; nt < 8; ++nt) {
                const float v = accB[nt][r] + accbuf[0][dr][nt * 16 + lane15]
                              + accbuf[1][dr][nt * 16 + lane15]
                              + accbuf[2][dr][nt * 16 + lane15];
                orow_p[nt * 16] = v * inv;
            }
        }
    }
}

extern "C" void kernel_launch(void* const* d_in, const int* in_sizes, int n_in,
                              void* d_out, int out_size, void* d_ws, size_t ws_size,
                              hipStream_t stream) {
    (void)in_sizes; (void)n_in; (void)out_size; (void)ws_size;
    const float* x  = (const float*)d_in[0];
    const int*  adj = (const int*)d_in[1];
    const float* W  = (const float*)d_in[2];
    const float* a  = (const float*)d_in[3];
    float* out = (float*)d_out;
    char* ws = (char*)d_ws;
    // ws use: 12.13 MB
    unsigned short* hTp = (unsigned short*)ws;                      // 4 MB  packed bf16
    float* s1 = (float*)(ws + (4 << 20));                           // 32 KB
    float* s2 = (float*)(ws + (4 << 20) + (32 << 10));              // 32 KB
    float* Mr = (float*)(ws + (4 << 20) + (96 << 10));              // 32 KB
    unsigned long long* mk = (unsigned long long*)(ws + (4 << 20) + (128 << 10)); // 8 MB

    k01<<<4608, 256, 0, stream>>>(x, W, hTp, a, adj, mk, s1, s2);
    kmax<<<2048, 256, 0, stream>>>((const unsigned*)mk, s2, Mr);
    k2_attn<<<512, 256, 0, stream>>>((const unsigned*)mk, hTp, s1, s2, Mr, out);
}